// Round 7
// baseline (677.228 us; speedup 1.0000x reference)
//
#include <hip/hip_runtime.h>
#include <cstdint>
#include <cstddef>

#define N_NODES 89250
#define M_PAD   89344   // 349 * 256
#define F0 500
#define F1 512
#define F2 256
#define F3 7
#define KP 512          // padded K for the MFMA GEMMs

typedef __attribute__((ext_vector_type(8))) short bf16x8;   // 8 bf16 = 4 VGPRs
typedef __attribute__((ext_vector_type(4))) float f32x4;

static inline int cdiv_i(int a, int b) { return (a + b - 1) / b; }

__device__ __forceinline__ unsigned short f2b(float f) {
  unsigned int u = __float_as_uint(f);
  u = (u + 0x7FFFu + ((u >> 16) & 1u)) >> 16;
  return (unsigned short)u;
}
__device__ __forceinline__ float b2f(unsigned short h) {
  return __uint_as_float(((unsigned int)h) << 16);
}

// ---------------- CSR build ----------------
__global__ void degree_kernel(const int* __restrict__ dst, int* __restrict__ cnt, int E) {
  int stride = gridDim.x * blockDim.x;
  for (int i = blockIdx.x * blockDim.x + threadIdx.x; i < E; i += stride)
    atomicAdd(&cnt[dst[i]], 1);
}

__global__ __launch_bounds__(1024) void scan_partial(const int* __restrict__ cnt,
                                                     int* __restrict__ row_ptr,
                                                     int* __restrict__ bsum, int n) {
  __shared__ int sm[1024];
  const int i = blockIdx.x * 1024 + threadIdx.x;
  const int v = (i < n) ? cnt[i] : 0;
  sm[threadIdx.x] = v;
  __syncthreads();
  for (int off = 1; off < 1024; off <<= 1) {
    int t = (threadIdx.x >= off) ? sm[threadIdx.x - off] : 0;
    __syncthreads();
    sm[threadIdx.x] += t;
    __syncthreads();
  }
  if (i < n) row_ptr[i] = sm[threadIdx.x] - v;    // block-local exclusive
  if (threadIdx.x == 1023) bsum[blockIdx.x] = sm[1023];
}

__global__ __launch_bounds__(1024) void scan_bsums(int* __restrict__ bsum, int nb) {
  __shared__ int sm[1024];
  const int v = (threadIdx.x < nb) ? bsum[threadIdx.x] : 0;
  sm[threadIdx.x] = v;
  __syncthreads();
  for (int off = 1; off < 1024; off <<= 1) {
    int t = (threadIdx.x >= off) ? sm[threadIdx.x - off] : 0;
    __syncthreads();
    sm[threadIdx.x] += t;
    __syncthreads();
  }
  if (threadIdx.x < nb) bsum[threadIdx.x] = sm[threadIdx.x] - v;  // exclusive
}

// adds block offsets AND initializes cursor = row_ptr (saves a pass)
__global__ __launch_bounds__(1024) void scan_add(int* __restrict__ row_ptr,
                                                 const int* __restrict__ bsum,
                                                 int* __restrict__ cursor,
                                                 int n, int total) {
  const int i = blockIdx.x * 1024 + threadIdx.x;
  if (i < n) {
    const int v = row_ptr[i] + bsum[i >> 10];
    row_ptr[i] = v;
    cursor[i] = v;
  }
  if (i == 0) row_ptr[n] = total;
}

__global__ void fill_kernel(const int* __restrict__ src, const int* __restrict__ dst,
                            int* __restrict__ cursor, int* __restrict__ csr_src, int E) {
  int stride = gridDim.x * blockDim.x;
  for (int i = blockIdx.x * blockDim.x + threadIdx.x; i < E; i += stride) {
    const int p = atomicAdd(&cursor[dst[i]], 1);
    csr_src[p] = src[i];
  }
}

// ---------------- conversions to bf16 ----------------
__global__ __launch_bounds__(256) void convert_x_kernel(const float* __restrict__ x,
                                                        unsigned short* __restrict__ xb) {
  const long long total = (long long)M_PAD * (KP / 8);
  const long long stride = (long long)gridDim.x * blockDim.x;
  for (long long idx = (long long)blockIdx.x * blockDim.x + threadIdx.x; idx < total; idx += stride) {
    const int node = (int)(idx >> 6);
    const int c8 = ((int)idx & 63) * 8;
    unsigned short r[8];
#pragma unroll
    for (int j = 0; j < 8; ++j) {
      const int c = c8 + j;
      float v = 0.0f;
      if (node < N_NODES && c < F0) v = x[(size_t)node * F0 + c];
      r[j] = f2b(v);
    }
    *reinterpret_cast<uint4*>(xb + (size_t)node * KP + c8) = *reinterpret_cast<const uint4*>(r);
  }
}

// all weights in one kernel: wl1/wr1 [512,500]->[512,512]; wl2/wr2 [256,512]->w2b concat;
// wl3/wr3 [7,256] -> w3b [16,256] (rows 0..6 = wl3, 8..14 = wr3, 7/15 zero)
__global__ __launch_bounds__(256) void convert_w_all(
    const float* __restrict__ wl1, const float* __restrict__ wr1,
    const float* __restrict__ wl2, const float* __restrict__ wr2,
    const float* __restrict__ wl3, const float* __restrict__ wr3,
    unsigned short* __restrict__ wl1b, unsigned short* __restrict__ wr1b,
    unsigned short* __restrict__ w2b, unsigned short* __restrict__ w3b)
{
  int idx = blockIdx.x * 256 + threadIdx.x;
  const int S1 = F1 * KP;          // 262144, covers wl1 AND wr1
  if (idx < S1) {
    const int j = idx >> 9, k = idx & 511;
    const bool in = (k < F0);
    wl1b[idx] = in ? f2b(wl1[(size_t)j * F0 + k]) : (unsigned short)0;
    wr1b[idx] = in ? f2b(wr1[(size_t)j * F0 + k]) : (unsigned short)0;
    return;
  }
  idx -= S1;
  const int S2 = F2 * KP;          // 131072, covers wl2 AND wr2 (K=512 exact)
  if (idx < S2) {
    w2b[idx] = f2b(wl2[idx]);
    w2b[S2 + idx] = f2b(wr2[idx]);
    return;
  }
  idx -= S2;
  if (idx < 16 * 256) {
    const int j = idx >> 8, k = idx & 255;
    float v = 0.0f;
    if (j < 7) v = wl3[(size_t)j * F2 + k];
    else if (j >= 8 && j < 15) v = wr3[(size_t)(j - 8) * F2 + k];
    w3b[idx] = f2b(v);
  }
}

// ---------------- gather-mean (bf16 in/out, f32 accum), C=512, wave per node ----------------
__global__ __launch_bounds__(256) void gather_mean_bf512(
    const unsigned short* __restrict__ xb, const int* __restrict__ row_ptr,
    const int* __restrict__ csr_src, unsigned short* __restrict__ aggb)
{
  const int node = blockIdx.x * 4 + (threadIdx.x >> 6);
  const int t = threadIdx.x & 63;
  if (node >= M_PAD) return;
  if (node >= N_NODES) {                // zero pad rows (ws is not re-zeroed between replays)
    *reinterpret_cast<uint4*>(aggb + (size_t)node * 512 + t * 8) = make_uint4(0, 0, 0, 0);
    return;
  }
  const int beg = row_ptr[node];
  const int end = row_ptr[node + 1];
  float acc[8] = {0.f, 0.f, 0.f, 0.f, 0.f, 0.f, 0.f, 0.f};
  for (int j = beg; j < end; j += 8) {
    uint4 v[8];
    float m[8];
#pragma unroll
    for (int u = 0; u < 8; ++u) {
      const int e = min(j + u, end - 1);
      m[u] = (j + u < end) ? 1.0f : 0.0f;
      v[u] = *reinterpret_cast<const uint4*>(xb + (size_t)csr_src[e] * 512 + t * 8);
    }
#pragma unroll
    for (int u = 0; u < 8; ++u) {
      const unsigned int w[4] = {v[u].x, v[u].y, v[u].z, v[u].w};
#pragma unroll
      for (int q = 0; q < 4; ++q) {
        acc[2 * q]     = fmaf(m[u], b2f((unsigned short)(w[q] & 0xFFFF)), acc[2 * q]);
        acc[2 * q + 1] = fmaf(m[u], b2f((unsigned short)(w[q] >> 16)),    acc[2 * q + 1]);
      }
    }
  }
  const int deg = end - beg;
  const float inv = 1.0f / (float)(deg > 1 ? deg : 1);
  unsigned short r[8];
#pragma unroll
  for (int q = 0; q < 8; ++q) r[q] = f2b(acc[q] * inv);
  *reinterpret_cast<uint4*>(aggb + (size_t)node * 512 + t * 8) = *reinterpret_cast<const uint4*>(r);
}

// ---------------- 256x256 8-wave bf16 MFMA GEMM, double-buffered LDS + counted vmcnt ----------------
// nt K-tiles of BK=64; tile t<8 uses A1/B1, t>=8 uses A2/B2 (K=512 each source).
// Per tile: [B1 barrier] STAGE(t+1) [vmcnt(8)] [B2 barrier] 4 quadrant-phases (64 MFMA/wave).
// Counted vmcnt(8) keeps next tile's 8 global_load_lds in flight across the compute (T4).
__global__ __launch_bounds__(512) void gemm_mfma256(
    const unsigned short* __restrict__ A1, const unsigned short* __restrict__ A2,
    const unsigned short* __restrict__ B1, const unsigned short* __restrict__ B2,
    const float* __restrict__ bias, unsigned short* __restrict__ Cout,
    int J, int nt, int fuse, int relu)
{
  __shared__ __align__(16) unsigned short Alds[2][256 * 64];
  __shared__ __align__(16) unsigned short Blds[2][256 * 64];
  const int tid = threadIdx.x;
  const int lane = tid & 63;
  const int w = tid >> 6;             // 8 waves
  const int wm = w >> 2;              // 2 row-groups of 128
  const int wn = w & 3;               // 4 col-groups of 64

  // bijective XCD swizzle (m204; nwg % 8 != 0 safe)
  int wg = blockIdx.x;
  {
    const int nwg = gridDim.x;
    const int q = nwg >> 3, r = nwg & 7;
    const int xcd = wg & 7, o = wg >> 3;
    wg = (xcd < r ? xcd * (q + 1) : r * (q + 1) + (xcd - r) * q) + o;
  }
  const int ncol = J >> 8;            // J/256 col-blocks
  const int brow = (wg / ncol) * 256; // consecutive wg share the A row-panel (L2 reuse)
  const int bcol = (wg % ncol) * 256;

  f32x4 acc[8][4];
#pragma unroll
  for (int m = 0; m < 8; ++m)
#pragma unroll
    for (int n = 0; n < 4; ++n) acc[m][n] = (f32x4){0.f, 0.f, 0.f, 0.f};

  const int fr = lane & 15;           // fragment row/col within 16
  const int fk = lane >> 4;           // fragment k-group (8 elems)
  // staging: per thread 4 A-loads + 4 B-loads of 16B; T2 source pre-swizzle (rule 21)
  const int srow_lo = lane >> 3;      // 0..7 within the wave's 8-row stripe
  const int schunk = (lane & 7) ^ (srow_lo & 7);

  auto STAGE = [&](int t) {
    const unsigned short* __restrict__ A = (t < 8) ? A1 : A2;
    const unsigned short* __restrict__ B = (t < 8) ? B1 : B2;
    const int k0 = (t & 7) * 64;
    const int buf = t & 1;
#pragma unroll
    for (int i = 0; i < 4; ++i) {
      const int rbase = i * 64 + w * 8;           // wave-uniform 8-row stripe
      const int row = rbase + srow_lo;
      __builtin_amdgcn_global_load_lds(
          (const __attribute__((address_space(1))) unsigned int*)(A + (size_t)(brow + row) * KP + k0 + schunk * 8),
          (__attribute__((address_space(3))) unsigned int*)(&Alds[buf][rbase * 64]),
          16, 0, 0);
      __builtin_amdgcn_global_load_lds(
          (const __attribute__((address_space(1))) unsigned int*)(B + (size_t)(bcol + row) * KP + k0 + schunk * 8),
          (__attribute__((address_space(3))) unsigned int*)(&Blds[buf][rbase * 64]),
          16, 0, 0);
    }
  };

  STAGE(0);   // prologue: tile 0 in flight (8 loads/thread)

  for (int t = 0; t < nt; ++t) {
    // B1: all waves finished reading buf[(t+1)&1] (tile t-1) -> safe to overwrite
    asm volatile("s_barrier" ::: "memory");
    if (t + 1 < nt) {
      STAGE(t + 1);                                  // prefetch into the freed buffer
      asm volatile("s_waitcnt vmcnt(8)" ::: "memory");   // tile t's 8 loads done; t+1's stay in flight
    } else {
      asm volatile("s_waitcnt vmcnt(0)" ::: "memory");   // epilogue drain
    }
    // B2: every wave verified its own tile-t loads -> whole tile staged
    asm volatile("s_barrier" ::: "memory");

    const int buf = t & 1;
    bf16x8 bfr[2][4];
#pragma unroll
    for (int q = 0; q < 4; ++q) {
      const int mh = q & 1;            // row-half of the wave's 128 rows
      const int ks = q >> 1;           // k-slice (16x16x32 granule)
      bf16x8 a[4];
#pragma unroll
      for (int m = 0; m < 4; ++m) {
        const int row = wm * 128 + (mh * 4 + m) * 16 + fr;
        const int ch = (ks * 4 + fk) ^ (row & 7);
        a[m] = *reinterpret_cast<const bf16x8*>(&Alds[buf][row * 64 + ch * 8]);
      }
      if (mh == 0) {
#pragma unroll
        for (int n = 0; n < 4; ++n) {
          const int row = wn * 64 + n * 16 + fr;
          const int ch = (ks * 4 + fk) ^ (row & 7);
          bfr[ks][n] = *reinterpret_cast<const bf16x8*>(&Blds[buf][row * 64 + ch * 8]);
        }
      }
      __builtin_amdgcn_s_setprio(1);
#pragma unroll
      for (int m = 0; m < 4; ++m)
#pragma unroll
        for (int n = 0; n < 4; ++n)
          acc[mh * 4 + m][n] = __builtin_amdgcn_mfma_f32_16x16x32_bf16(a[m], bfr[ks][n], acc[mh * 4 + m][n], 0, 0, 0);
      __builtin_amdgcn_s_setprio(0);
    }
  }

  // epilogue: C/D layout col=lane&15, row=(lane>>4)*4+i  [m89-verified]
  const int crow0 = brow + wm * 128 + (lane >> 4) * 4;
  const int ccol0 = bcol + wn * 64 + fr;
#pragma unroll
  for (int n = 0; n < 4; ++n) {
    const int col = ccol0 + n * 16;
    const float bv = fuse ? bias[col] : 0.0f;
#pragma unroll
    for (int m = 0; m < 8; ++m) {
#pragma unroll
      for (int i = 0; i < 4; ++i) {
        const int row = crow0 + m * 16 + i;
        float v = acc[m][n][i] + bv;
        if (relu) v = fmaxf(v, 0.0f);
        Cout[(size_t)row * J + col] = f2b(v);
      }
    }
  }
}

// ---------------- combine layer 2: h2 = relu(mean-gather(y2[:, :256]) + y2[i, 256:] + b2) ----------------
__global__ __launch_bounds__(256) void combine2_kernel(
    const unsigned short* __restrict__ y, const int* __restrict__ row_ptr,
    const int* __restrict__ csr_src, const float* __restrict__ bias,
    unsigned short* __restrict__ h)
{
  const int node = blockIdx.x * 8 + (threadIdx.x >> 5);
  const int t = threadIdx.x & 31;        // 8 channels each -> 256
  if (node >= N_NODES) return;
  const int beg = row_ptr[node];
  const int end = row_ptr[node + 1];
  float acc[8] = {0.f, 0.f, 0.f, 0.f, 0.f, 0.f, 0.f, 0.f};
  for (int j = beg; j < end; j += 8) {
    uint4 v[8];
    float m[8];
#pragma unroll
    for (int u = 0; u < 8; ++u) {
      const int e = min(j + u, end - 1);
      m[u] = (j + u < end) ? 1.0f : 0.0f;
      v[u] = *reinterpret_cast<const uint4*>(y + (size_t)csr_src[e] * 512 + t * 8);
    }
#pragma unroll
    for (int u = 0; u < 8; ++u) {
      const unsigned int w[4] = {v[u].x, v[u].y, v[u].z, v[u].w};
#pragma unroll
      for (int q = 0; q < 4; ++q) {
        acc[2 * q]     = fmaf(m[u], b2f((unsigned short)(w[q] & 0xFFFF)), acc[2 * q]);
        acc[2 * q + 1] = fmaf(m[u], b2f((unsigned short)(w[q] >> 16)),    acc[2 * q + 1]);
      }
    }
  }
  const int deg = end - beg;
  const float inv = 1.0f / (float)(deg > 1 ? deg : 1);
  const uint4 rv = *reinterpret_cast<const uint4*>(y + (size_t)node * 512 + 256 + t * 8);
  const unsigned int ru[4] = {rv.x, rv.y, rv.z, rv.w};
  unsigned short r[8];
#pragma unroll
  for (int q = 0; q < 4; ++q) {
    const float y0 = b2f((unsigned short)(ru[q] & 0xFFFF));
    const float y1 = b2f((unsigned short)(ru[q] >> 16));
    const float c0 = acc[2 * q] * inv + y0 + bias[t * 8 + 2 * q];
    const float c1 = acc[2 * q + 1] * inv + y1 + bias[t * 8 + 2 * q + 1];
    r[2 * q]     = f2b(fmaxf(c0, 0.0f));
    r[2 * q + 1] = f2b(fmaxf(c1, 0.0f));
  }
  *reinterpret_cast<uint4*>(h + (size_t)node * 256 + t * 8) = *reinterpret_cast<const uint4*>(r);
}

// ---------------- layer 3 projection via MFMA: y3[M,16] = h2 @ w3b.T ----------------
__global__ __launch_bounds__(256) void gemm3_mfma(
    const unsigned short* __restrict__ h2b, const unsigned short* __restrict__ w3b,
    unsigned short* __restrict__ y3)
{
  const int wave = threadIdx.x >> 6, lane = threadIdx.x & 63;
  const int rowbase = blockIdx.x * 64 + wave * 16;
  const int fr = lane & 15, fk = lane >> 4;
  bf16x8 b[8];
#pragma unroll
  for (int ks = 0; ks < 8; ++ks)
    b[ks] = *reinterpret_cast<const bf16x8*>(w3b + fr * 256 + ks * 32 + fk * 8);
  f32x4 acc = (f32x4){0.f, 0.f, 0.f, 0.f};
#pragma unroll
  for (int ks = 0; ks < 8; ++ks) {
    const bf16x8 a = *reinterpret_cast<const bf16x8*>(h2b + (size_t)(rowbase + fr) * 256 + ks * 32 + fk * 8);
    acc = __builtin_amdgcn_mfma_f32_16x16x32_bf16(a, b[ks], acc, 0, 0, 0);
  }
  const int r0 = rowbase + fk * 4;
#pragma unroll
  for (int i = 0; i < 4; ++i)
    y3[(size_t)(r0 + i) * 16 + fr] = f2b(acc[i]);
}

// ---------------- combine layer 3: out = mean-gather(y3[:, 0..6]) + y3[i, 8..14] + b3 ----------------
__global__ __launch_bounds__(256) void combine3_kernel(
    const unsigned short* __restrict__ y3, const int* __restrict__ row_ptr,
    const int* __restrict__ csr_src, const float* __restrict__ b3,
    float* __restrict__ out, int N)
{
  const int node = blockIdx.x * 4 + (threadIdx.x >> 6);
  const int lane = threadIdx.x & 63;
  if (node >= N) return;
  const int beg = row_ptr[node];
  const int end = row_ptr[node + 1];
  float acc[7] = {0.f, 0.f, 0.f, 0.f, 0.f, 0.f, 0.f};
  for (int j = beg + lane; j < end; j += 64) {
    const int s = csr_src[j];
    const uint4 v = *reinterpret_cast<const uint4*>(y3 + (size_t)s * 16);
    const unsigned int u[4] = {v.x, v.y, v.z, v.w};
#pragma unroll
    for (int q = 0; q < 7; ++q) {
      const unsigned short hw = (unsigned short)((u[q >> 1] >> ((q & 1) * 16)) & 0xFFFF);
      acc[q] += b2f(hw);
    }
  }
#pragma unroll
  for (int q = 0; q < 7; ++q)
#pragma unroll
    for (int m = 1; m < 64; m <<= 1)
      acc[q] += __shfl_xor(acc[q], m, 64);
  if (lane == 0) {
    const int deg = end - beg;
    const float inv = 1.0f / (float)(deg > 1 ? deg : 1);
    const uint4 rv = *reinterpret_cast<const uint4*>(y3 + (size_t)node * 16 + 8);
    const unsigned int ru[4] = {rv.x, rv.y, rv.z, rv.w};
#pragma unroll
    for (int q = 0; q < 7; ++q) {
      const float self = b2f((unsigned short)((ru[q >> 1] >> ((q & 1) * 16)) & 0xFFFF));
      out[(size_t)node * F3 + q] = acc[q] * inv + self + b3[q];
    }
  }
}

extern "C" void kernel_launch(void* const* d_in, const int* in_sizes, int n_in,
                              void* d_out, int out_size, void* d_ws, size_t ws_size,
                              hipStream_t stream) {
  const float* x    = (const float*)d_in[0];
  const int*   ei   = (const int*)d_in[1];
  const float* w_l1 = (const float*)d_in[2];
  const float* w_r1 = (const float*)d_in[3];
  const float* b1   = (const float*)d_in[4];
  const float* w_l2 = (const float*)d_in[5];
  const float* w_r2 = (const float*)d_in[6];
  const float* b2   = (const float*)d_in[7];
  const float* w_l3 = (const float*)d_in[8];
  const float* w_r3 = (const float*)d_in[9];
  const float* b3   = (const float*)d_in[10];
  float* out = (float*)d_out;

  const int E = in_sizes[1] / 2;
  const int* src = ei;
  const int* dst = ei + E;

  // ---- workspace carve-up
  char* p = (char*)d_ws;
  int* row_ptr = (int*)p;           p += (size_t)(N_NODES + 1) * 4;
  int* cnt     = (int*)p;           p += (size_t)N_NODES * 4;
  int* bsum    = (int*)p;           p += 1024 * 4;
  int* csr_src = (int*)p;           p += (size_t)E * 4;
  p = (char*)(((uintptr_t)p + 255) & ~(uintptr_t)255);
  unsigned short* xb   = (unsigned short*)p;  p += (size_t)M_PAD * KP * 2;  // also reused as y2
  unsigned short* aggb = (unsigned short*)p;  p += (size_t)M_PAD * KP * 2;  // also reused as h2
  unsigned short* h1b  = (unsigned short*)p;  p += (size_t)M_PAD * KP * 2;  // also reused as y3
  unsigned short* wl1b = (unsigned short*)p;  p += (size_t)F1 * KP * 2;
  unsigned short* wr1b = (unsigned short*)p;  p += (size_t)F1 * KP * 2;
  unsigned short* w2b  = (unsigned short*)p;  p += (size_t)F1 * KP * 2;     // concat [wl2; wr2] -> 512 rows
  unsigned short* w3b  = (unsigned short*)p;  p += (size_t)16 * F2 * 2;     // [16,256]

  unsigned short* y2  = xb;     // [M_PAD, 512]; xb dead after GEMM1
  unsigned short* h2b = aggb;   // [M_PAD, 256]; aggb dead after GEMM1
  unsigned short* y3  = h1b;    // [M_PAD, 16];  h1b dead after GEMM2

  const int nb = cdiv_i(N_NODES, 1024);   // 88

  // ---- CSR build
  hipMemsetAsync(cnt, 0, (size_t)N_NODES * sizeof(int), stream);
  degree_kernel<<<cdiv_i(E, 256), 256, 0, stream>>>(dst, cnt, E);
  scan_partial<<<nb, 1024, 0, stream>>>(cnt, row_ptr, bsum, N_NODES);
  scan_bsums<<<1, 1024, 0, stream>>>(bsum, nb);
  scan_add<<<nb, 1024, 0, stream>>>(row_ptr, bsum, cnt, N_NODES, E);   // cnt becomes cursor
  fill_kernel<<<cdiv_i(E, 256), 256, 0, stream>>>(src, dst, cnt, csr_src, E);

  // ---- conversions
  convert_x_kernel<<<2048, 256, 0, stream>>>(x, xb);
  {
    const int total = F1 * KP + F2 * KP + 16 * F2;
    convert_w_all<<<cdiv_i(total, 256), 256, 0, stream>>>(
        w_l1, w_r1, w_l2, w_r2, w_l3, w_r3, wl1b, wr1b, w2b, w3b);
  }

  // ---- layer 1: agg = mean-gather(x);  h1 = relu(agg@wl1.T + x@wr1.T + b1)
  gather_mean_bf512<<<cdiv_i(M_PAD, 4), 256, 0, stream>>>(xb, row_ptr, csr_src, aggb);
  gemm_mfma256<<<(M_PAD / 256) * 2, 512, 0, stream>>>(aggb, xb, wl1b, wr1b, b1, h1b, F1, 16, 1, 1);

  // ---- layer 2 (aggregate AFTER projection): y2 = h1 @ [wl2; wr2].T, then combine
  gemm_mfma256<<<(M_PAD / 256) * 2, 512, 0, stream>>>(h1b, h1b, w2b, w2b, (const float*)nullptr, y2, 512, 8, 0, 0);
  combine2_kernel<<<cdiv_i(N_NODES, 8), 256, 0, stream>>>(y2, row_ptr, csr_src, b2, h2b);

  // ---- layer 3: MFMA projection to [M,16], then combine
  gemm3_mfma<<<M_PAD / 64, 256, 0, stream>>>(h2b, w3b, y3);
  combine3_kernel<<<cdiv_i(N_NODES, 4), 256, 0, stream>>>(y3, row_ptr, csr_src, b3, out, N_NODES);
}

// Round 8
// 652.079 us; speedup vs baseline: 1.0386x; 1.0386x over previous
//
#include <hip/hip_runtime.h>
#include <cstdint>
#include <cstddef>

#define N_NODES 89250
#define M_PAD   89344   // 698 * 128
#define F0 500
#define F1 512
#define F2 256
#define F3 7
#define KP 512          // padded K for the MFMA GEMMs

typedef __attribute__((ext_vector_type(8))) short bf16x8;   // 8 bf16 = 4 VGPRs
typedef __attribute__((ext_vector_type(4))) float f32x4;

static inline int cdiv_i(int a, int b) { return (a + b - 1) / b; }

__device__ __forceinline__ unsigned short f2b(float f) {
  unsigned int u = __float_as_uint(f);
  u = (u + 0x7FFFu + ((u >> 16) & 1u)) >> 16;
  return (unsigned short)u;
}
__device__ __forceinline__ float b2f(unsigned short h) {
  return __uint_as_float(((unsigned int)h) << 16);
}

// ---------------- CSR build ----------------
__global__ void degree_kernel(const int* __restrict__ dst, int* __restrict__ cnt, int E) {
  int stride = gridDim.x * blockDim.x;
  for (int i = blockIdx.x * blockDim.x + threadIdx.x; i < E; i += stride)
    atomicAdd(&cnt[dst[i]], 1);
}

__global__ __launch_bounds__(1024) void scan_partial(const int* __restrict__ cnt,
                                                     int* __restrict__ row_ptr,
                                                     int* __restrict__ bsum, int n) {
  __shared__ int sm[1024];
  const int i = blockIdx.x * 1024 + threadIdx.x;
  const int v = (i < n) ? cnt[i] : 0;
  sm[threadIdx.x] = v;
  __syncthreads();
  for (int off = 1; off < 1024; off <<= 1) {
    int t = (threadIdx.x >= off) ? sm[threadIdx.x - off] : 0;
    __syncthreads();
    sm[threadIdx.x] += t;
    __syncthreads();
  }
  if (i < n) row_ptr[i] = sm[threadIdx.x] - v;    // block-local exclusive
  if (threadIdx.x == 1023) bsum[blockIdx.x] = sm[1023];
}

__global__ __launch_bounds__(1024) void scan_bsums(int* __restrict__ bsum, int nb) {
  __shared__ int sm[1024];
  const int v = (threadIdx.x < nb) ? bsum[threadIdx.x] : 0;
  sm[threadIdx.x] = v;
  __syncthreads();
  for (int off = 1; off < 1024; off <<= 1) {
    int t = (threadIdx.x >= off) ? sm[threadIdx.x - off] : 0;
    __syncthreads();
    sm[threadIdx.x] += t;
    __syncthreads();
  }
  if (threadIdx.x < nb) bsum[threadIdx.x] = sm[threadIdx.x] - v;  // exclusive
}

// adds block offsets AND initializes cursor = row_ptr (saves a pass)
__global__ __launch_bounds__(1024) void scan_add(int* __restrict__ row_ptr,
                                                 const int* __restrict__ bsum,
                                                 int* __restrict__ cursor,
                                                 int n, int total) {
  const int i = blockIdx.x * 1024 + threadIdx.x;
  if (i < n) {
    const int v = row_ptr[i] + bsum[i >> 10];
    row_ptr[i] = v;
    cursor[i] = v;
  }
  if (i == 0) row_ptr[n] = total;
}

__global__ void fill_kernel(const int* __restrict__ src, const int* __restrict__ dst,
                            int* __restrict__ cursor, int* __restrict__ csr_src, int E) {
  int stride = gridDim.x * blockDim.x;
  for (int i = blockIdx.x * blockDim.x + threadIdx.x; i < E; i += stride) {
    const int p = atomicAdd(&cursor[dst[i]], 1);
    csr_src[p] = src[i];
  }
}

// ---------------- conversions to bf16 ----------------
__global__ __launch_bounds__(256) void convert_x_kernel(const float* __restrict__ x,
                                                        unsigned short* __restrict__ xb) {
  const long long total = (long long)M_PAD * (KP / 8);
  const long long stride = (long long)gridDim.x * blockDim.x;
  for (long long idx = (long long)blockIdx.x * blockDim.x + threadIdx.x; idx < total; idx += stride) {
    const int node = (int)(idx >> 6);
    const int c8 = ((int)idx & 63) * 8;
    unsigned short r[8];
#pragma unroll
    for (int j = 0; j < 8; ++j) {
      const int c = c8 + j;
      float v = 0.0f;
      if (node < N_NODES && c < F0) v = x[(size_t)node * F0 + c];
      r[j] = f2b(v);
    }
    *reinterpret_cast<uint4*>(xb + (size_t)node * KP + c8) = *reinterpret_cast<const uint4*>(r);
  }
}

// all weights in one kernel: wl1/wr1 [512,500]->[512,512]; wl2/wr2 [256,512]->w2b concat;
// wl3/wr3 [7,256] -> w3b [16,256] (rows 0..6 = wl3, 8..14 = wr3, 7/15 zero)
__global__ __launch_bounds__(256) void convert_w_all(
    const float* __restrict__ wl1, const float* __restrict__ wr1,
    const float* __restrict__ wl2, const float* __restrict__ wr2,
    const float* __restrict__ wl3, const float* __restrict__ wr3,
    unsigned short* __restrict__ wl1b, unsigned short* __restrict__ wr1b,
    unsigned short* __restrict__ w2b, unsigned short* __restrict__ w3b)
{
  int idx = blockIdx.x * 256 + threadIdx.x;
  const int S1 = F1 * KP;          // 262144, covers wl1 AND wr1
  if (idx < S1) {
    const int j = idx >> 9, k = idx & 511;
    const bool in = (k < F0);
    wl1b[idx] = in ? f2b(wl1[(size_t)j * F0 + k]) : (unsigned short)0;
    wr1b[idx] = in ? f2b(wr1[(size_t)j * F0 + k]) : (unsigned short)0;
    return;
  }
  idx -= S1;
  const int S2 = F2 * KP;          // 131072, covers wl2 AND wr2 (K=512 exact)
  if (idx < S2) {
    w2b[idx] = f2b(wl2[idx]);
    w2b[S2 + idx] = f2b(wr2[idx]);
    return;
  }
  idx -= S2;
  if (idx < 16 * 256) {
    const int j = idx >> 8, k = idx & 255;
    float v = 0.0f;
    if (j < 7) v = wl3[(size_t)j * F2 + k];
    else if (j >= 8 && j < 15) v = wr3[(size_t)(j - 8) * F2 + k];
    w3b[idx] = f2b(v);
  }
}

// ---------------- gather-mean (bf16 in/out, f32 accum), C=512, wave per node ----------------
__global__ __launch_bounds__(256) void gather_mean_bf512(
    const unsigned short* __restrict__ xb, const int* __restrict__ row_ptr,
    const int* __restrict__ csr_src, unsigned short* __restrict__ aggb)
{
  const int node = blockIdx.x * 4 + (threadIdx.x >> 6);
  const int t = threadIdx.x & 63;
  if (node >= M_PAD) return;
  if (node >= N_NODES) {                // zero pad rows (ws is not re-zeroed between replays)
    *reinterpret_cast<uint4*>(aggb + (size_t)node * 512 + t * 8) = make_uint4(0, 0, 0, 0);
    return;
  }
  const int beg = row_ptr[node];
  const int end = row_ptr[node + 1];
  float acc[8] = {0.f, 0.f, 0.f, 0.f, 0.f, 0.f, 0.f, 0.f};
  for (int j = beg; j < end; j += 8) {
    uint4 v[8];
    float m[8];
#pragma unroll
    for (int u = 0; u < 8; ++u) {
      const int e = min(j + u, end - 1);
      m[u] = (j + u < end) ? 1.0f : 0.0f;
      v[u] = *reinterpret_cast<const uint4*>(xb + (size_t)csr_src[e] * 512 + t * 8);
    }
#pragma unroll
    for (int u = 0; u < 8; ++u) {
      const unsigned int w[4] = {v[u].x, v[u].y, v[u].z, v[u].w};
#pragma unroll
      for (int q = 0; q < 4; ++q) {
        acc[2 * q]     = fmaf(m[u], b2f((unsigned short)(w[q] & 0xFFFF)), acc[2 * q]);
        acc[2 * q + 1] = fmaf(m[u], b2f((unsigned short)(w[q] >> 16)),    acc[2 * q + 1]);
      }
    }
  }
  const int deg = end - beg;
  const float inv = 1.0f / (float)(deg > 1 ? deg : 1);
  unsigned short r[8];
#pragma unroll
  for (int q = 0; q < 8; ++q) r[q] = f2b(acc[q] * inv);
  *reinterpret_cast<uint4*>(aggb + (size_t)node * 512 + t * 8) = *reinterpret_cast<const uint4*>(r);
}

// ---------------- 128x128 4-wave bf16 MFMA GEMM, TRUE double-buffer + T3-minimal pipeline ----------------
// Per K-tile: STAGE(t+1) -> compute tile t (ds_read + 32 MFMA/wave) -> vmcnt(0) -> s_barrier.
// vmcnt(0) sits AFTER the compute so tile t+1's loads hide under the MFMAs; one barrier per tile.
// 64KB LDS -> 2 blocks/CU so barrier stalls are covered by the co-resident block.
// niter=16: C = A1@B1.T + A2@B2.T (K=512 each);  niter=8: C = A1@B1.T.
__global__ __launch_bounds__(256) void gemm_mfma(
    const unsigned short* __restrict__ A1, const unsigned short* __restrict__ A2,
    const unsigned short* __restrict__ B1, const unsigned short* __restrict__ B2,
    const float* __restrict__ bias, unsigned short* __restrict__ Cout,
    int J, int niter, int fuse, int relu)
{
  __shared__ __align__(16) unsigned short Alds[2][128 * 64];
  __shared__ __align__(16) unsigned short Blds[2][128 * 64];
  const int tid = threadIdx.x;
  const int lane = tid & 63;
  const int wid = tid >> 6;          // 4 waves

  // XCD chunk swizzle over col-major flatten (nwg % 8 == 0: 2792 for both shapes)
  const int nwg = gridDim.x * gridDim.y;
  int wg = blockIdx.y * gridDim.x + blockIdx.x;
  const int cpx = nwg >> 3;
  wg = (wg & 7) * cpx + (wg >> 3);
  const int brow = (wg / gridDim.y) * 128;   // consecutive wg on an XCD share the A row-panel
  const int bcol = (wg % gridDim.y) * 128;

  const int wr = wid >> 1;           // wave's 64x64 quadrant
  const int wc = wid & 1;

  f32x4 acc[4][4];
#pragma unroll
  for (int m = 0; m < 4; ++m)
#pragma unroll
    for (int n = 0; n < 4; ++n) acc[m][n] = (f32x4){0.f, 0.f, 0.f, 0.f};

  const int srow = lane >> 3;            // 0..7: row within 8-row stripe
  const int schunk = (lane & 7) ^ srow;  // T2: pre-swizzled source 16B-chunk (rule 21)
  const int fr = lane & 15;              // fragment row/col
  const int fk = lane >> 4;              // fragment k-group (8 elems)

  auto STAGE = [&](int t) {
    const unsigned short* __restrict__ A = (t < 8) ? A1 : A2;
    const unsigned short* __restrict__ B = (t < 8) ? B1 : B2;
    const int k0 = (t & 7) * 64;
    const int buf = t & 1;
#pragma unroll
    for (int i = 0; i < 4; ++i) {
      const int rbase = i * 32 + wid * 8;      // wave-uniform 8-row stripe
      const int row = rbase + srow;
      __builtin_amdgcn_global_load_lds(
          (const __attribute__((address_space(1))) unsigned int*)(A + (size_t)(brow + row) * KP + k0 + schunk * 8),
          (__attribute__((address_space(3))) unsigned int*)(&Alds[buf][rbase * 64]),
          16, 0, 0);
      __builtin_amdgcn_global_load_lds(
          (const __attribute__((address_space(1))) unsigned int*)(B + (size_t)(bcol + row) * KP + k0 + schunk * 8),
          (__attribute__((address_space(3))) unsigned int*)(&Blds[buf][rbase * 64]),
          16, 0, 0);
    }
  };

  STAGE(0);                                     // prologue: tile 0 (8 loads/thread)
  asm volatile("s_waitcnt vmcnt(0)" ::: "memory");
  asm volatile("s_barrier" ::: "memory");

  for (int t = 0; t < niter; ++t) {
    if (t + 1 < niter) STAGE(t + 1);            // prefetch into the other buffer (stays in flight)
    const int buf = t & 1;
#pragma unroll
    for (int ks = 0; ks < 2; ++ks) {
      bf16x8 a[4], b[4];
#pragma unroll
      for (int m = 0; m < 4; ++m) {
        const int row = wr * 64 + m * 16 + fr;
        a[m] = *reinterpret_cast<const bf16x8*>(&Alds[buf][row * 64 + (((ks * 4 + fk) ^ (row & 7)) * 8)]);
      }
#pragma unroll
      for (int n = 0; n < 4; ++n) {
        const int row = wc * 64 + n * 16 + fr;
        b[n] = *reinterpret_cast<const bf16x8*>(&Blds[buf][row * 64 + (((ks * 4 + fk) ^ (row & 7)) * 8)]);
      }
      __builtin_amdgcn_s_setprio(1);
#pragma unroll
      for (int m = 0; m < 4; ++m)
#pragma unroll
        for (int n = 0; n < 4; ++n)
          acc[m][n] = __builtin_amdgcn_mfma_f32_16x16x32_bf16(a[m], b[n], acc[m][n], 0, 0, 0);
      __builtin_amdgcn_s_setprio(0);
    }
    // tile t+1 staged (loads had the whole compute phase to land) AND all waves done reading buf
    asm volatile("s_waitcnt vmcnt(0)" ::: "memory");
    asm volatile("s_barrier" ::: "memory");
  }

  // epilogue: C/D layout col=lane&15, row=(lane>>4)*4+i  [m89-verified]
  const int crow0 = brow + wr * 64 + (lane >> 4) * 4;
  const int ccol0 = bcol + wc * 64 + (lane & 15);
#pragma unroll
  for (int n = 0; n < 4; ++n) {
    const int col = ccol0 + n * 16;
    const float bv = fuse ? bias[col] : 0.0f;
#pragma unroll
    for (int m = 0; m < 4; ++m) {
#pragma unroll
      for (int i = 0; i < 4; ++i) {
        const int row = crow0 + m * 16 + i;
        float v = acc[m][n][i] + bv;
        if (relu) v = fmaxf(v, 0.0f);
        Cout[(size_t)row * J + col] = f2b(v);
      }
    }
  }
}

// ---------------- combine layer 2: h2 = relu(mean-gather(y2[:, :256]) + y2[i, 256:] + b2) ----------------
__global__ __launch_bounds__(256) void combine2_kernel(
    const unsigned short* __restrict__ y, const int* __restrict__ row_ptr,
    const int* __restrict__ csr_src, const float* __restrict__ bias,
    unsigned short* __restrict__ h)
{
  const int node = blockIdx.x * 8 + (threadIdx.x >> 5);
  const int t = threadIdx.x & 31;        // 8 channels each -> 256
  if (node >= N_NODES) return;
  const int beg = row_ptr[node];
  const int end = row_ptr[node + 1];
  float acc[8] = {0.f, 0.f, 0.f, 0.f, 0.f, 0.f, 0.f, 0.f};
  for (int j = beg; j < end; j += 8) {
    uint4 v[8];
    float m[8];
#pragma unroll
    for (int u = 0; u < 8; ++u) {
      const int e = min(j + u, end - 1);
      m[u] = (j + u < end) ? 1.0f : 0.0f;
      v[u] = *reinterpret_cast<const uint4*>(y + (size_t)csr_src[e] * 512 + t * 8);
    }
#pragma unroll
    for (int u = 0; u < 8; ++u) {
      const unsigned int w[4] = {v[u].x, v[u].y, v[u].z, v[u].w};
#pragma unroll
      for (int q = 0; q < 4; ++q) {
        acc[2 * q]     = fmaf(m[u], b2f((unsigned short)(w[q] & 0xFFFF)), acc[2 * q]);
        acc[2 * q + 1] = fmaf(m[u], b2f((unsigned short)(w[q] >> 16)),    acc[2 * q + 1]);
      }
    }
  }
  const int deg = end - beg;
  const float inv = 1.0f / (float)(deg > 1 ? deg : 1);
  const uint4 rv = *reinterpret_cast<const uint4*>(y + (size_t)node * 512 + 256 + t * 8);
  const unsigned int ru[4] = {rv.x, rv.y, rv.z, rv.w};
  unsigned short r[8];
#pragma unroll
  for (int q = 0; q < 4; ++q) {
    const float y0 = b2f((unsigned short)(ru[q] & 0xFFFF));
    const float y1 = b2f((unsigned short)(ru[q] >> 16));
    const float c0 = acc[2 * q] * inv + y0 + bias[t * 8 + 2 * q];
    const float c1 = acc[2 * q + 1] * inv + y1 + bias[t * 8 + 2 * q + 1];
    r[2 * q]     = f2b(fmaxf(c0, 0.0f));
    r[2 * q + 1] = f2b(fmaxf(c1, 0.0f));
  }
  *reinterpret_cast<uint4*>(h + (size_t)node * 256 + t * 8) = *reinterpret_cast<const uint4*>(r);
}

// ---------------- layer 3 projection via MFMA: y3[M,16] = h2 @ w3b.T ----------------
__global__ __launch_bounds__(256) void gemm3_mfma(
    const unsigned short* __restrict__ h2b, const unsigned short* __restrict__ w3b,
    unsigned short* __restrict__ y3)
{
  const int wave = threadIdx.x >> 6, lane = threadIdx.x & 63;
  const int rowbase = blockIdx.x * 64 + wave * 16;
  const int fr = lane & 15, fk = lane >> 4;
  bf16x8 b[8];
#pragma unroll
  for (int ks = 0; ks < 8; ++ks)
    b[ks] = *reinterpret_cast<const bf16x8*>(w3b + fr * 256 + ks * 32 + fk * 8);
  f32x4 acc = (f32x4){0.f, 0.f, 0.f, 0.f};
#pragma unroll
  for (int ks = 0; ks < 8; ++ks) {
    const bf16x8 a = *reinterpret_cast<const bf16x8*>(h2b + (size_t)(rowbase + fr) * 256 + ks * 32 + fk * 8);
    acc = __builtin_amdgcn_mfma_f32_16x16x32_bf16(a, b[ks], acc, 0, 0, 0);
  }
  const int r0 = rowbase + fk * 4;
#pragma unroll
  for (int i = 0; i < 4; ++i)
    y3[(size_t)(r0 + i) * 16 + fr] = f2b(acc[i]);
}

// ---------------- combine layer 3: out = mean-gather(y3[:, 0..6]) + y3[i, 8..14] + b3 ----------------
__global__ __launch_bounds__(256) void combine3_kernel(
    const unsigned short* __restrict__ y3, const int* __restrict__ row_ptr,
    const int* __restrict__ csr_src, const float* __restrict__ b3,
    float* __restrict__ out, int N)
{
  const int node = blockIdx.x * 4 + (threadIdx.x >> 6);
  const int lane = threadIdx.x & 63;
  if (node >= N) return;
  const int beg = row_ptr[node];
  const int end = row_ptr[node + 1];
  float acc[7] = {0.f, 0.f, 0.f, 0.f, 0.f, 0.f, 0.f};
  for (int j = beg + lane; j < end; j += 64) {
    const int s = csr_src[j];
    const uint4 v = *reinterpret_cast<const uint4*>(y3 + (size_t)s * 16);
    const unsigned int u[4] = {v.x, v.y, v.z, v.w};
#pragma unroll
    for (int q = 0; q < 7; ++q) {
      const unsigned short hw = (unsigned short)((u[q >> 1] >> ((q & 1) * 16)) & 0xFFFF);
      acc[q] += b2f(hw);
    }
  }
#pragma unroll
  for (int q = 0; q < 7; ++q)
#pragma unroll
    for (int m = 1; m < 64; m <<= 1)
      acc[q] += __shfl_xor(acc[q], m, 64);
  if (lane == 0) {
    const int deg = end - beg;
    const float inv = 1.0f / (float)(deg > 1 ? deg : 1);
    const uint4 rv = *reinterpret_cast<const uint4*>(y3 + (size_t)node * 16 + 8);
    const unsigned int ru[4] = {rv.x, rv.y, rv.z, rv.w};
#pragma unroll
    for (int q = 0; q < 7; ++q) {
      const float self = b2f((unsigned short)((ru[q >> 1] >> ((q & 1) * 16)) & 0xFFFF));
      out[(size_t)node * F3 + q] = acc[q] * inv + self + b3[q];
    }
  }
}

extern "C" void kernel_launch(void* const* d_in, const int* in_sizes, int n_in,
                              void* d_out, int out_size, void* d_ws, size_t ws_size,
                              hipStream_t stream) {
  const float* x    = (const float*)d_in[0];
  const int*   ei   = (const int*)d_in[1];
  const float* w_l1 = (const float*)d_in[2];
  const float* w_r1 = (const float*)d_in[3];
  const float* b1   = (const float*)d_in[4];
  const float* w_l2 = (const float*)d_in[5];
  const float* w_r2 = (const float*)d_in[6];
  const float* b2   = (const float*)d_in[7];
  const float* w_l3 = (const float*)d_in[8];
  const float* w_r3 = (const float*)d_in[9];
  const float* b3   = (const float*)d_in[10];
  float* out = (float*)d_out;

  const int E = in_sizes[1] / 2;
  const int* src = ei;
  const int* dst = ei + E;

  // ---- workspace carve-up
  char* p = (char*)d_ws;
  int* row_ptr = (int*)p;           p += (size_t)(N_NODES + 1) * 4;
  int* cnt     = (int*)p;           p += (size_t)N_NODES * 4;
  int* bsum    = (int*)p;           p += 1024 * 4;
  int* csr_src = (int*)p;           p += (size_t)E * 4;
  p = (char*)(((uintptr_t)p + 255) & ~(uintptr_t)255);
  unsigned short* xb   = (unsigned short*)p;  p += (size_t)M_PAD * KP * 2;  // also reused as y2
  unsigned short* aggb = (unsigned short*)p;  p += (size_t)M_PAD * KP * 2;  // also reused as h2
  unsigned short* h1b  = (unsigned short*)p;  p += (size_t)M_PAD * KP * 2;  // also reused as y3
  unsigned short* wl1b = (unsigned short*)p;  p += (size_t)F1 * KP * 2;
  unsigned short* wr1b = (unsigned short*)p;  p += (size_t)F1 * KP * 2;
  unsigned short* w2b  = (unsigned short*)p;  p += (size_t)F1 * KP * 2;     // concat [wl2; wr2] -> 512 rows
  unsigned short* w3b  = (unsigned short*)p;  p += (size_t)16 * F2 * 2;     // [16,256]

  unsigned short* y2  = xb;     // [M_PAD, 512]; xb dead after GEMM1
  unsigned short* h2b = aggb;   // [M_PAD, 256]; aggb dead after GEMM1
  unsigned short* y3  = h1b;    // [M_PAD, 16];  h1b dead after GEMM2

  const int nb = cdiv_i(N_NODES, 1024);   // 88

  // ---- CSR build
  hipMemsetAsync(cnt, 0, (size_t)N_NODES * sizeof(int), stream);
  degree_kernel<<<cdiv_i(E, 256), 256, 0, stream>>>(dst, cnt, E);
  scan_partial<<<nb, 1024, 0, stream>>>(cnt, row_ptr, bsum, N_NODES);
  scan_bsums<<<1, 1024, 0, stream>>>(bsum, nb);
  scan_add<<<nb, 1024, 0, stream>>>(row_ptr, bsum, cnt, N_NODES, E);   // cnt becomes cursor
  fill_kernel<<<cdiv_i(E, 256), 256, 0, stream>>>(src, dst, cnt, csr_src, E);

  // ---- conversions
  convert_x_kernel<<<2048, 256, 0, stream>>>(x, xb);
  {
    const int total = F1 * KP + F2 * KP + 16 * F2;
    convert_w_all<<<cdiv_i(total, 256), 256, 0, stream>>>(
        w_l1, w_r1, w_l2, w_r2, w_l3, w_r3, wl1b, wr1b, w2b, w3b);
  }

  // ---- layer 1: agg = mean-gather(x);  h1 = relu(agg@wl1.T + x@wr1.T + b1)
  gather_mean_bf512<<<cdiv_i(M_PAD, 4), 256, 0, stream>>>(xb, row_ptr, csr_src, aggb);
  {
    dim3 g(M_PAD / 128, F1 / 128);
    gemm_mfma<<<g, 256, 0, stream>>>(aggb, xb, wl1b, wr1b, b1, h1b, F1, 16, 1, 1);
  }

  // ---- layer 2 (aggregate AFTER projection): y2 = h1 @ [wl2; wr2].T, then combine
  {
    dim3 g(M_PAD / 128, 512 / 128);
    gemm_mfma<<<g, 256, 0, stream>>>(h1b, h1b, w2b, w2b, (const float*)nullptr, y2, 512, 8, 0, 0);
  }
  combine2_kernel<<<cdiv_i(N_NODES, 8), 256, 0, stream>>>(y2, row_ptr, csr_src, b2, h2b);

  // ---- layer 3: MFMA projection to [M,16], then combine
  gemm3_mfma<<<M_PAD / 64, 256, 0, stream>>>(h2b, w3b, y3);
  combine3_kernel<<<cdiv_i(N_NODES, 4), 256, 0, stream>>>(y3, row_ptr, csr_src, b3, out, N_NODES);
}

// Round 9
// 637.483 us; speedup vs baseline: 1.0623x; 1.0229x over previous
//
#include <hip/hip_runtime.h>
#include <cstdint>
#include <cstddef>

#define N_NODES 89250
#define M_PAD   89344   // 698 * 128
#define F0 500
#define F1 512
#define F2 256
#define F3 7
#define KP 512          // padded K for the MFMA GEMMs

typedef __attribute__((ext_vector_type(8))) short bf16x8;   // 8 bf16 = 4 VGPRs
typedef __attribute__((ext_vector_type(4))) float f32x4;

static inline int cdiv_i(int a, int b) { return (a + b - 1) / b; }

__device__ __forceinline__ unsigned short f2b(float f) {
  unsigned int u = __float_as_uint(f);
  u = (u + 0x7FFFu + ((u >> 16) & 1u)) >> 16;
  return (unsigned short)u;
}
__device__ __forceinline__ float b2f(unsigned short h) {
  return __uint_as_float(((unsigned int)h) << 16);
}

// ---------------- CSR build ----------------
__global__ void degree_kernel(const int* __restrict__ dst, int* __restrict__ cnt, int E) {
  int stride = gridDim.x * blockDim.x;
  for (int i = blockIdx.x * blockDim.x + threadIdx.x; i < E; i += stride)
    atomicAdd(&cnt[dst[i]], 1);
}

__global__ __launch_bounds__(1024) void scan_partial(const int* __restrict__ cnt,
                                                     int* __restrict__ row_ptr,
                                                     int* __restrict__ bsum, int n) {
  __shared__ int sm[1024];
  const int i = blockIdx.x * 1024 + threadIdx.x;
  const int v = (i < n) ? cnt[i] : 0;
  sm[threadIdx.x] = v;
  __syncthreads();
  for (int off = 1; off < 1024; off <<= 1) {
    int t = (threadIdx.x >= off) ? sm[threadIdx.x - off] : 0;
    __syncthreads();
    sm[threadIdx.x] += t;
    __syncthreads();
  }
  if (i < n) row_ptr[i] = sm[threadIdx.x] - v;    // block-local exclusive
  if (threadIdx.x == 1023) bsum[blockIdx.x] = sm[1023];
}

__global__ __launch_bounds__(1024) void scan_bsums(int* __restrict__ bsum, int nb) {
  __shared__ int sm[1024];
  const int v = (threadIdx.x < nb) ? bsum[threadIdx.x] : 0;
  sm[threadIdx.x] = v;
  __syncthreads();
  for (int off = 1; off < 1024; off <<= 1) {
    int t = (threadIdx.x >= off) ? sm[threadIdx.x - off] : 0;
    __syncthreads();
    sm[threadIdx.x] += t;
    __syncthreads();
  }
  if (threadIdx.x < nb) bsum[threadIdx.x] = sm[threadIdx.x] - v;  // exclusive
}

// adds block offsets AND initializes cursor = row_ptr (saves a pass)
__global__ __launch_bounds__(1024) void scan_add(int* __restrict__ row_ptr,
                                                 const int* __restrict__ bsum,
                                                 int* __restrict__ cursor,
                                                 int n, int total) {
  const int i = blockIdx.x * 1024 + threadIdx.x;
  if (i < n) {
    const int v = row_ptr[i] + bsum[i >> 10];
    row_ptr[i] = v;
    cursor[i] = v;
  }
  if (i == 0) row_ptr[n] = total;
}

__global__ void fill_kernel(const int* __restrict__ src, const int* __restrict__ dst,
                            int* __restrict__ cursor, int* __restrict__ csr_src, int E) {
  int stride = gridDim.x * blockDim.x;
  for (int i = blockIdx.x * blockDim.x + threadIdx.x; i < E; i += stride) {
    const int p = atomicAdd(&cursor[dst[i]], 1);
    csr_src[p] = src[i];
  }
}

// ---------------- fused conversion: x + all weights (block-range split) ----------------
// blocks [0, XBLK): x [N,500] f32 -> xb [M_PAD,512] bf16 (zero pad).
// blocks [XBLK, ...): wl1/wr1 -> [512,512]; wl2/wr2 -> w2b concat [512,512];
//                     wl3/wr3 -> w3b [16,256] (rows 0..6 = wl3, 8..14 = wr3, 7/15 zero)
#define XBLK (M_PAD * 64 / 256)     // 22336
__global__ __launch_bounds__(256) void prep_kernel(
    const float* __restrict__ x,
    const float* __restrict__ wl1, const float* __restrict__ wr1,
    const float* __restrict__ wl2, const float* __restrict__ wr2,
    const float* __restrict__ wl3, const float* __restrict__ wr3,
    unsigned short* __restrict__ xb,
    unsigned short* __restrict__ wl1b, unsigned short* __restrict__ wr1b,
    unsigned short* __restrict__ w2b, unsigned short* __restrict__ w3b)
{
  if (blockIdx.x < XBLK) {
    const int idx = blockIdx.x * 256 + threadIdx.x;   // uint4 granule
    const int node = idx >> 6;
    const int c8 = (idx & 63) * 8;
    unsigned short r[8];
#pragma unroll
    for (int j = 0; j < 8; ++j) {
      const int c = c8 + j;
      float v = 0.0f;
      if (node < N_NODES && c < F0) v = x[(size_t)node * F0 + c];
      r[j] = f2b(v);
    }
    *reinterpret_cast<uint4*>(xb + (size_t)node * KP + c8) = *reinterpret_cast<const uint4*>(r);
    return;
  }
  int idx = (blockIdx.x - XBLK) * 256 + threadIdx.x;
  const int S1 = F1 * KP;          // 262144, covers wl1 AND wr1
  if (idx < S1) {
    const int j = idx >> 9, k = idx & 511;
    const bool in = (k < F0);
    wl1b[idx] = in ? f2b(wl1[(size_t)j * F0 + k]) : (unsigned short)0;
    wr1b[idx] = in ? f2b(wr1[(size_t)j * F0 + k]) : (unsigned short)0;
    return;
  }
  idx -= S1;
  const int S2 = F2 * KP;          // 131072, covers wl2 AND wr2 (K=512 exact)
  if (idx < S2) {
    w2b[idx] = f2b(wl2[idx]);
    w2b[S2 + idx] = f2b(wr2[idx]);
    return;
  }
  idx -= S2;
  if (idx < 16 * 256) {
    const int j = idx >> 8, k = idx & 255;
    float v = 0.0f;
    if (j < 7) v = wl3[(size_t)j * F2 + k];
    else if (j >= 8 && j < 15) v = wr3[(size_t)(j - 8) * F2 + k];
    w3b[idx] = f2b(v);
  }
}

// ---------------- gather-mean (bf16 in/out, f32 accum), C=512, wave per node ----------------
__global__ __launch_bounds__(256) void gather_mean_bf512(
    const unsigned short* __restrict__ xb, const int* __restrict__ row_ptr,
    const int* __restrict__ csr_src, unsigned short* __restrict__ aggb)
{
  const int node = blockIdx.x * 4 + (threadIdx.x >> 6);
  const int t = threadIdx.x & 63;
  if (node >= M_PAD) return;
  if (node >= N_NODES) {                // zero pad rows (ws is not re-zeroed between replays)
    *reinterpret_cast<uint4*>(aggb + (size_t)node * 512 + t * 8) = make_uint4(0, 0, 0, 0);
    return;
  }
  const int beg = row_ptr[node];
  const int end = row_ptr[node + 1];
  float acc[8] = {0.f, 0.f, 0.f, 0.f, 0.f, 0.f, 0.f, 0.f};
  for (int j = beg; j < end; j += 8) {
    uint4 v[8];
    float m[8];
#pragma unroll
    for (int u = 0; u < 8; ++u) {
      const int e = min(j + u, end - 1);
      m[u] = (j + u < end) ? 1.0f : 0.0f;
      v[u] = *reinterpret_cast<const uint4*>(xb + (size_t)csr_src[e] * 512 + t * 8);
    }
#pragma unroll
    for (int u = 0; u < 8; ++u) {
      const unsigned int w[4] = {v[u].x, v[u].y, v[u].z, v[u].w};
#pragma unroll
      for (int q = 0; q < 4; ++q) {
        acc[2 * q]     = fmaf(m[u], b2f((unsigned short)(w[q] & 0xFFFF)), acc[2 * q]);
        acc[2 * q + 1] = fmaf(m[u], b2f((unsigned short)(w[q] >> 16)),    acc[2 * q + 1]);
      }
    }
  }
  const int deg = end - beg;
  const float inv = 1.0f / (float)(deg > 1 ? deg : 1);
  unsigned short r[8];
#pragma unroll
  for (int q = 0; q < 8; ++q) r[q] = f2b(acc[q] * inv);
  *reinterpret_cast<uint4*>(aggb + (size_t)node * 512 + t * 8) = *reinterpret_cast<const uint4*>(r);
}

// ---------------- 128x128 4-wave bf16 MFMA GEMM (R6 single-buffer; proven best) ----------------
// niter=16: C = A1@B1.T + A2@B2.T (K=512 each);  niter=8: C = A1@B1.T.
__global__ __launch_bounds__(256) void gemm_mfma(
    const unsigned short* __restrict__ A1, const unsigned short* __restrict__ A2,
    const unsigned short* __restrict__ B1, const unsigned short* __restrict__ B2,
    const float* __restrict__ bias, unsigned short* __restrict__ Cout,
    int J, int niter, int fuse, int relu)
{
  __shared__ __align__(16) unsigned short Alds[128 * 64];
  __shared__ __align__(16) unsigned short Blds[128 * 64];
  const int tid = threadIdx.x;
  const int lane = tid & 63;
  const int wid = tid >> 6;          // 4 waves

  // XCD chunk swizzle over col-major flatten (nwg % 8 == 0: 2792/1396 for our shapes)
  const int nwg = gridDim.x * gridDim.y;
  int wg = blockIdx.y * gridDim.x + blockIdx.x;
  const int cpx = nwg >> 3;
  wg = (wg & 7) * cpx + (wg >> 3);
  const int brow = (wg / gridDim.y) * 128;   // consecutive wg on an XCD share the A row-panel
  const int bcol = (wg % gridDim.y) * 128;

  const int wr = wid >> 1;           // wave's 64x64 quadrant
  const int wc = wid & 1;

  f32x4 acc[4][4];
#pragma unroll
  for (int m = 0; m < 4; ++m)
#pragma unroll
    for (int n = 0; n < 4; ++n) acc[m][n] = (f32x4){0.f, 0.f, 0.f, 0.f};

  const int srow = lane >> 3;            // 0..7: row within 8-row stripe
  const int schunk = (lane & 7) ^ srow;  // T2: pre-swizzled source 16B-chunk (rule 21)
  const int fr = lane & 15;              // fragment row/col
  const int fk = lane >> 4;              // fragment k-group (8 elems)

  for (int it = 0; it < niter; ++it) {
    const unsigned short* __restrict__ A = (it < 8) ? A1 : A2;
    const unsigned short* __restrict__ B = (it < 8) ? B1 : B2;
    const int k0 = (it & 7) * 64;
    __syncthreads();                 // previous tile's reads done before overwrite
#pragma unroll
    for (int i = 0; i < 4; ++i) {
      const int rbase = i * 32 + wid * 8;   // wave-uniform 8-row stripe
      const int row = rbase + srow;
      __builtin_amdgcn_global_load_lds(
          (const __attribute__((address_space(1))) unsigned int*)(A + (size_t)(brow + row) * KP + k0 + schunk * 8),
          (__attribute__((address_space(3))) unsigned int*)(&Alds[rbase * 64]),
          16, 0, 0);
      __builtin_amdgcn_global_load_lds(
          (const __attribute__((address_space(1))) unsigned int*)(B + (size_t)(bcol + row) * KP + k0 + schunk * 8),
          (__attribute__((address_space(3))) unsigned int*)(&Blds[rbase * 64]),
          16, 0, 0);
    }
    __syncthreads();                 // staging visible (compiler drains vmcnt)
#pragma unroll
    for (int ks = 0; ks < 2; ++ks) {
      bf16x8 a[4], b[4];
#pragma unroll
      for (int m = 0; m < 4; ++m) {
        const int row = wr * 64 + m * 16 + fr;
        a[m] = *reinterpret_cast<const bf16x8*>(&Alds[row * 64 + (((ks * 4 + fk) ^ (row & 7)) * 8)]);
      }
#pragma unroll
      for (int n = 0; n < 4; ++n) {
        const int row = wc * 64 + n * 16 + fr;
        b[n] = *reinterpret_cast<const bf16x8*>(&Blds[row * 64 + (((ks * 4 + fk) ^ (row & 7)) * 8)]);
      }
#pragma unroll
      for (int m = 0; m < 4; ++m)
#pragma unroll
        for (int n = 0; n < 4; ++n)
          acc[m][n] = __builtin_amdgcn_mfma_f32_16x16x32_bf16(a[m], b[n], acc[m][n], 0, 0, 0);
    }
  }

  // epilogue: C/D layout col=lane&15, row=(lane>>4)*4+i  [m89-verified]
  const int crow0 = brow + wr * 64 + (lane >> 4) * 4;
  const int ccol0 = bcol + wc * 64 + (lane & 15);
#pragma unroll
  for (int n = 0; n < 4; ++n) {
    const int col = ccol0 + n * 16;
    const float bv = fuse ? bias[col] : 0.0f;
#pragma unroll
    for (int m = 0; m < 4; ++m) {
#pragma unroll
      for (int i = 0; i < 4; ++i) {
        const int row = crow0 + m * 16 + i;
        float v = acc[m][n][i] + bv;
        if (relu) v = fmaxf(v, 0.0f);
        Cout[(size_t)row * J + col] = f2b(v);
      }
    }
  }
}

// ---------------- fused layer-2 combine + layer-3 projection ----------------
// per node: h2 = relu(mean-gather(y2[:, :256]) + y2[i, 256:] + b2)   (kept in f32 regs)
//           y3[n, 0..6] = h2 @ wl3.T,  y3[n, 8..14] = h2 @ wr3.T     (w3b rows 0..6 / 8..14)
__global__ __launch_bounds__(256) void combine2p3_kernel(
    const unsigned short* __restrict__ y, const int* __restrict__ row_ptr,
    const int* __restrict__ csr_src, const float* __restrict__ bias,
    const unsigned short* __restrict__ w3b, unsigned short* __restrict__ y3)
{
  __shared__ unsigned short w3s[16 * 256];
  {
    const int t0 = threadIdx.x * 16;
    *reinterpret_cast<uint4*>(&w3s[t0])     = *reinterpret_cast<const uint4*>(&w3b[t0]);
    *reinterpret_cast<uint4*>(&w3s[t0 + 8]) = *reinterpret_cast<const uint4*>(&w3b[t0 + 8]);
  }
  __syncthreads();

  const int node = blockIdx.x * 8 + (threadIdx.x >> 5);
  const int t = threadIdx.x & 31;        // 8 channels each -> 256
  if (node >= N_NODES) return;
  const int beg = row_ptr[node];
  const int end = row_ptr[node + 1];
  float acc[8] = {0.f, 0.f, 0.f, 0.f, 0.f, 0.f, 0.f, 0.f};
  for (int j = beg; j < end; j += 8) {
    uint4 v[8];
    float m[8];
#pragma unroll
    for (int u = 0; u < 8; ++u) {
      const int e = min(j + u, end - 1);
      m[u] = (j + u < end) ? 1.0f : 0.0f;
      v[u] = *reinterpret_cast<const uint4*>(y + (size_t)csr_src[e] * 512 + t * 8);
    }
#pragma unroll
    for (int u = 0; u < 8; ++u) {
      const unsigned int w[4] = {v[u].x, v[u].y, v[u].z, v[u].w};
#pragma unroll
      for (int q = 0; q < 4; ++q) {
        acc[2 * q]     = fmaf(m[u], b2f((unsigned short)(w[q] & 0xFFFF)), acc[2 * q]);
        acc[2 * q + 1] = fmaf(m[u], b2f((unsigned short)(w[q] >> 16)),    acc[2 * q + 1]);
      }
    }
  }
  const int deg = end - beg;
  const float inv = 1.0f / (float)(deg > 1 ? deg : 1);
  const uint4 rv = *reinterpret_cast<const uint4*>(y + (size_t)node * 512 + 256 + t * 8);
  const unsigned int ru[4] = {rv.x, rv.y, rv.z, rv.w};
  float c[8];
#pragma unroll
  for (int q = 0; q < 4; ++q) {
    const float y0 = b2f((unsigned short)(ru[q] & 0xFFFF));
    const float y1 = b2f((unsigned short)(ru[q] >> 16));
    c[2 * q]     = fmaxf(acc[2 * q] * inv + y0 + bias[t * 8 + 2 * q], 0.0f);
    c[2 * q + 1] = fmaxf(acc[2 * q + 1] * inv + y1 + bias[t * 8 + 2 * q + 1], 0.0f);
  }
  // layer-3 projection: 14 output dots, 32-lane tree reduce (lanes 0-31 / 32-63 independent)
#pragma unroll
  for (int jj = 0; jj < 14; ++jj) {
    const int row = jj + (jj >= 7 ? 1 : 0);      // skip padding rows 7/15
    const uint4 wv = *reinterpret_cast<const uint4*>(&w3s[row * 256 + t * 8]);
    const unsigned int wu[4] = {wv.x, wv.y, wv.z, wv.w};
    float s = 0.0f;
#pragma unroll
    for (int q = 0; q < 4; ++q) {
      s = fmaf(c[2 * q],     b2f((unsigned short)(wu[q] & 0xFFFF)), s);
      s = fmaf(c[2 * q + 1], b2f((unsigned short)(wu[q] >> 16)),    s);
    }
#pragma unroll
    for (int m = 1; m < 32; m <<= 1) s += __shfl_xor(s, m, 64);
    if (t == 0) y3[(size_t)node * 16 + row] = f2b(s);
  }
}

// ---------------- combine layer 3: out = mean-gather(y3[:, 0..6]) + y3[i, 8..14] + b3 ----------------
__global__ __launch_bounds__(256) void combine3_kernel(
    const unsigned short* __restrict__ y3, const int* __restrict__ row_ptr,
    const int* __restrict__ csr_src, const float* __restrict__ b3,
    float* __restrict__ out, int N)
{
  const int node = blockIdx.x * 4 + (threadIdx.x >> 6);
  const int lane = threadIdx.x & 63;
  if (node >= N) return;
  const int beg = row_ptr[node];
  const int end = row_ptr[node + 1];
  float acc[7] = {0.f, 0.f, 0.f, 0.f, 0.f, 0.f, 0.f};
  for (int j = beg + lane; j < end; j += 64) {
    const int s = csr_src[j];
    const uint4 v = *reinterpret_cast<const uint4*>(y3 + (size_t)s * 16);
    const unsigned int u[4] = {v.x, v.y, v.z, v.w};
#pragma unroll
    for (int q = 0; q < 7; ++q) {
      const unsigned short hw = (unsigned short)((u[q >> 1] >> ((q & 1) * 16)) & 0xFFFF);
      acc[q] += b2f(hw);
    }
  }
#pragma unroll
  for (int q = 0; q < 7; ++q)
#pragma unroll
    for (int m = 1; m < 64; m <<= 1)
      acc[q] += __shfl_xor(acc[q], m, 64);
  if (lane == 0) {
    const int deg = end - beg;
    const float inv = 1.0f / (float)(deg > 1 ? deg : 1);
    const uint4 rv = *reinterpret_cast<const uint4*>(y3 + (size_t)node * 16 + 8);
    const unsigned int ru[4] = {rv.x, rv.y, rv.z, rv.w};
#pragma unroll
    for (int q = 0; q < 7; ++q) {
      const float self = b2f((unsigned short)((ru[q >> 1] >> ((q & 1) * 16)) & 0xFFFF));
      out[(size_t)node * F3 + q] = acc[q] * inv + self + b3[q];
    }
  }
}

extern "C" void kernel_launch(void* const* d_in, const int* in_sizes, int n_in,
                              void* d_out, int out_size, void* d_ws, size_t ws_size,
                              hipStream_t stream) {
  const float* x    = (const float*)d_in[0];
  const int*   ei   = (const int*)d_in[1];
  const float* w_l1 = (const float*)d_in[2];
  const float* w_r1 = (const float*)d_in[3];
  const float* b1   = (const float*)d_in[4];
  const float* w_l2 = (const float*)d_in[5];
  const float* w_r2 = (const float*)d_in[6];
  const float* b2   = (const float*)d_in[7];
  const float* w_l3 = (const float*)d_in[8];
  const float* w_r3 = (const float*)d_in[9];
  const float* b3   = (const float*)d_in[10];
  float* out = (float*)d_out;

  const int E = in_sizes[1] / 2;
  const int* src = ei;
  const int* dst = ei + E;

  // ---- workspace carve-up
  char* p = (char*)d_ws;
  int* row_ptr = (int*)p;           p += (size_t)(N_NODES + 1) * 4;
  int* cnt     = (int*)p;           p += (size_t)N_NODES * 4;
  int* bsum    = (int*)p;           p += 1024 * 4;
  int* csr_src = (int*)p;           p += (size_t)E * 4;
  p = (char*)(((uintptr_t)p + 255) & ~(uintptr_t)255);
  unsigned short* xb   = (unsigned short*)p;  p += (size_t)M_PAD * KP * 2;  // also reused as y2
  unsigned short* aggb = (unsigned short*)p;  p += (size_t)M_PAD * KP * 2;
  unsigned short* h1b  = (unsigned short*)p;  p += (size_t)M_PAD * KP * 2;  // also reused as y3
  unsigned short* wl1b = (unsigned short*)p;  p += (size_t)F1 * KP * 2;
  unsigned short* wr1b = (unsigned short*)p;  p += (size_t)F1 * KP * 2;
  unsigned short* w2b  = (unsigned short*)p;  p += (size_t)F1 * KP * 2;     // concat [wl2; wr2] -> 512 rows
  unsigned short* w3b  = (unsigned short*)p;  p += (size_t)16 * F2 * 2;     // [16,256]

  unsigned short* y2  = xb;     // [M_PAD, 512]; xb dead after GEMM1
  unsigned short* y3  = h1b;    // [M_PAD, 16];  h1b dead after GEMM2

  const int nb = cdiv_i(N_NODES, 1024);   // 88

  // ---- CSR build
  hipMemsetAsync(cnt, 0, (size_t)N_NODES * sizeof(int), stream);
  degree_kernel<<<cdiv_i(E, 256), 256, 0, stream>>>(dst, cnt, E);
  scan_partial<<<nb, 1024, 0, stream>>>(cnt, row_ptr, bsum, N_NODES);
  scan_bsums<<<1, 1024, 0, stream>>>(bsum, nb);
  scan_add<<<nb, 1024, 0, stream>>>(row_ptr, bsum, cnt, N_NODES, E);   // cnt becomes cursor
  fill_kernel<<<cdiv_i(E, 256), 256, 0, stream>>>(src, dst, cnt, csr_src, E);

  // ---- conversions (x + all weights, one kernel)
  {
    const int wblocks = cdiv_i(F1 * KP + F2 * KP + 16 * F2, 256);   // 1552
    prep_kernel<<<XBLK + wblocks, 256, 0, stream>>>(
        x, w_l1, w_r1, w_l2, w_r2, w_l3, w_r3, xb, wl1b, wr1b, w2b, w3b);
  }

  // ---- layer 1: agg = mean-gather(x);  h1 = relu(agg@wl1.T + x@wr1.T + b1)
  gather_mean_bf512<<<cdiv_i(M_PAD, 4), 256, 0, stream>>>(xb, row_ptr, csr_src, aggb);
  {
    dim3 g(M_PAD / 128, F1 / 128);
    gemm_mfma<<<g, 256, 0, stream>>>(aggb, xb, wl1b, wr1b, b1, h1b, F1, 16, 1, 1);
  }

  // ---- layer 2 (aggregate AFTER projection): y2 = h1 @ [wl2; wr2].T
  {
    dim3 g(M_PAD / 128, 512 / 128);
    gemm_mfma<<<g, 256, 0, stream>>>(h1b, h1b, w2b, w2b, (const float*)nullptr, y2, 512, 8, 0, 0);
  }
  // fused: combine layer 2 + project layer 3 (h2 never materialized)
  combine2p3_kernel<<<cdiv_i(N_NODES, 8), 256, 0, stream>>>(y2, row_ptr, csr_src, b2, w3b, y3);

  // ---- combine layer 3
  combine3_kernel<<<cdiv_i(N_NODES, 4), 256, 0, stream>>>(y3, row_ptr, csr_src, b3, out, N_NODES);
}